// Round 4
// 1412.924 us; speedup vs baseline: 1.1804x; 1.1804x over previous
//
#include <hip/hip_runtime.h>
#include <hip/hip_fp16.h>

#define HD 512
#define Bsz 64
#define Tlen 512
#define GB 4
#define RING 16

typedef _Float16 h2v __attribute__((ext_vector_type(2)));
typedef unsigned u32x4 __attribute__((ext_vector_type(4)));
typedef unsigned long long ull;

__device__ __forceinline__ float dot2acc(unsigned a, unsigned b, float c) {
    return __builtin_amdgcn_fdot2(__builtin_bit_cast(h2v, a),
                                  __builtin_bit_cast(h2v, b), c, false);
}

// 16B coherent (MALL) transfers — sc0 sc1, proven pattern from the baseline.
__device__ __forceinline__ u32x4 mall_ld16(const void* p) {
    u32x4 r;
    asm volatile("global_load_dwordx4 %0, %1, off sc0 sc1\n\ts_waitcnt vmcnt(0)"
                 : "=v"(r) : "v"(p) : "memory");
    return r;
}
__device__ __forceinline__ void mall_st16(void* p, u32x4 v) {
    asm volatile("global_store_dwordx4 %0, %1, off sc0 sc1"
                 :: "v"(p), "v"(v) : "memory");
}
__device__ __forceinline__ unsigned mall_ld4(const unsigned* p) {
    unsigned r;
    asm volatile("global_load_dword %0, %1, off sc0 sc1\n\ts_waitcnt vmcnt(0)"
                 : "=v"(r) : "v"(p) : "memory");
    return r;
}
__device__ __forceinline__ void mall_st4(unsigned* p, unsigned v) {
    asm volatile("global_store_dword %0, %1, off sc0 sc1"
                 :: "v"(p), "v"(v) : "memory");
}

// Sentinel check: ring slots are pre-filled with 0xFFFF halves (fp16 -NaN,
// never produced by tanh). A 16B chunk is valid iff no half is 0xFFFF.
// 16B stores are single transactions -> no torn chunks.
__device__ __forceinline__ bool valid8(u32x4 v) {
    unsigned bad = 0;
#pragma unroll
    for (int i = 0; i < 4; ++i) {
        bad |= ((v[i] & 0xFFFFu) == 0xFFFFu);
        bad |= ((v[i] >> 16)     == 0xFFFFu);
    }
    return bad == 0u;
}

// Fused readiness+data: retry-load a 16B ring chunk until valid. One MALL RT
// per iteration; replaces the baseline's flag-poll RT + data RT.
__device__ __forceinline__ u32x4 ring_wait16(const void* p) {
    u32x4 v;
    bool ok = false;
    for (;;) {
        if (!ok) { v = mall_ld16(p); ok = valid8(v); }
        if (!__any((int)(!ok))) break;
        __builtin_amdgcn_s_sleep(1);
    }
    return v;
}

__device__ __forceinline__ void cvt4s(_Float16* d, float4 v) {
    union { ull u; _Float16 h[4]; } t;
    t.h[0] = (_Float16)v.x; t.h[1] = (_Float16)v.y;
    t.h[2] = (_Float16)v.z; t.h[3] = (_Float16)v.w;
    *(ull*)d = t.u;
}

__device__ __forceinline__ void gemm4(const u32x4* __restrict__ Ip, const u32x4* wr,
                                      int kq, int kbase, float acc[2][4]) {
#pragma unroll
    for (int i = 0; i < 4; ++i) {
        const int k8 = kbase + kq + 16 * i;
        const u32x4 w0 = wr[i * 2 + 0], w1 = wr[i * 2 + 1];
#pragma unroll
        for (int b = 0; b < 4; ++b) {
            const u32x4 h = Ip[k8 * 4 + b];
#pragma unroll
            for (int e = 0; e < 4; ++e) {
                acc[0][b] = dot2acc(w0[e], h[e], acc[0][b]);
                acc[1][b] = dot2acc(w1[e], h[e], acc[1][b]);
            }
        }
    }
}

// ===========================================================================
// FAST VARIANT: full-length rings (one slot per timestep), sentinel-validated.
// No flags, no vmcnt drain before publish, no backpressure, fewer barriers.
// Requires ws_size >= 64MB (2 rings x Tlen*Bsz*HD*2B = 32MB each, 0xFF-wiped
// by the host each launch -> cross-run staleness impossible).
// ===========================================================================
__global__ __launch_bounds__(512, 1) void rnn_fullring(
    const float* __restrict__ x, const float* __restrict__ h0in,
    const float* __restrict__ Wih, const float* __restrict__ bih,
    const float* __restrict__ Whh, const float* __restrict__ bhh,
    _Float16* __restrict__ H0r, _Float16* __restrict__ H1r,
    float* __restrict__ out)
{
    __shared__ _Float16 inb[128 * GB * 8] __attribute__((aligned(16)));
    __shared__ float    part[256 * 17];
    __shared__ _Float16 hout[256] __attribute__((aligned(16)));

    const int bid = blockIdx.x;
    const int g   = bid & 15;
    const int sl  = bid >> 4;
    const int l   = sl >> 3;
    const int rb  = sl & 7;
    const int tid = threadIdx.x;
    const int rh = tid >> 8, kq = (tid >> 4) & 15, rq = tid & 15;

    u32x4 wreg[16];
    {
        const float* WI = Wih + (size_t)l * HD * HD;
        const float* WH = Whh + (size_t)l * HD * HD;
#pragma unroll
        for (int ph = 0; ph < 2; ++ph) {
            const float* W = ph ? WH : WI;
#pragma unroll
            for (int i = 0; i < 4; ++i)
#pragma unroll
                for (int ri = 0; ri < 2; ++ri) {
                    const int row = rb * 64 + rq + 16 * (2 * rh + ri);
                    const float* p = W + (size_t)row * HD + (kq + 16 * i) * 8;
                    union { u32x4 u; _Float16 h[8]; } v;
#pragma unroll
                    for (int e = 0; e < 8; ++e) v.h[e] = (_Float16)p[e];
                    wreg[ph * 8 + i * 2 + ri] = v.u;
                }
        }
    }

    float bias = 0.f;
    if (tid < 256) {
        const int rowg = rb * 64 + (tid & 63);
        bias = bih[l * HD + rowg] + bhh[l * HD + rowg];
    }

    _Float16* ringo = l ? H1r : H0r;
    const u32x4* Ip = (const u32x4*)inb;

    const int bb = tid >> 7;      // l=0 x-staging: batch-in-group
    const int k4 = tid & 127;     // l=0 x-staging: float4 chunk
    const int bglobS = g * GB + bb;

    float4 xreg;
    if (l == 0) xreg = *(const float4*)(x + (size_t)bglobS * Tlen * HD + k4 * 4);

    for (int t = 0; t < Tlen; ++t) {
        float acc[2][4] = {{0, 0, 0, 0}, {0, 0, 0, 0}};

        if (l == 0) {
            // ---- stage x_t (prefetched), compute ih half ----
            cvt4s(&inb[((k4 >> 1) * GB + bb) * 8 + (k4 & 1) * 4], xreg);
            __syncthreads();
            if (t + 1 < Tlen)
                xreg = *(const float4*)(x + ((size_t)bglobS * Tlen + t + 1) * HD + k4 * 4);
            gemm4(Ip, wreg, kq, 0, acc);
            // ---- stage hh input: fused ready+load retry on slot t-1 ----
            if (t == 0) {
                if (tid < 256) {
                    int b2 = tid >> 6, k8 = tid & 63;
                    const float* src = h0in + (size_t)(g * GB + b2) * HD + k8 * 8;
                    cvt4s(&inb[((64 + k8) * GB + b2) * 8],     *(const float4*)src);
                    cvt4s(&inb[((64 + k8) * GB + b2) * 8 + 4], *(const float4*)(src + 4));
                }
            } else if (tid < 256) {
                int b2 = tid >> 6, k8 = tid & 63;
                u32x4 v = ring_wait16(H0r + ((size_t)(t - 1) * Bsz + g * GB + b2) * HD + k8 * 8);
                *(u32x4*)&inb[((64 + k8) * GB + b2) * 8] = v;
            }
            __syncthreads();
            gemm4(Ip, wreg + 8, kq, 64, acc);
        } else {
            // ---- layer 1: stage h0_t (tid<256) and h1_{t-1} (tid>=256) ----
            if (tid < 256) {
                int b2 = tid >> 6, k8 = tid & 63;
                u32x4 v = ring_wait16(H0r + ((size_t)t * Bsz + g * GB + b2) * HD + k8 * 8);
                *(u32x4*)&inb[(k8 * GB + b2) * 8] = v;
            } else if (t == 0) {
                int t2 = tid - 256; int b2 = t2 >> 6, k8 = t2 & 63;
                const float* src = h0in + (size_t)(Bsz + g * GB + b2) * HD + k8 * 8;
                cvt4s(&inb[((64 + k8) * GB + b2) * 8],     *(const float4*)src);
                cvt4s(&inb[((64 + k8) * GB + b2) * 8 + 4], *(const float4*)(src + 4));
            } else {
                int t2 = tid - 256; int b2 = t2 >> 6, k8 = t2 & 63;
                u32x4 v = ring_wait16(H1r + ((size_t)(t - 1) * Bsz + g * GB + b2) * HD + k8 * 8);
                *(u32x4*)&inb[((64 + k8) * GB + b2) * 8] = v;
            }
            __syncthreads();
            gemm4(Ip, wreg, kq, 0, acc);
            gemm4(Ip, wreg + 8, kq, 64, acc);
        }

        // ---- reduce across kq, tanh, outputs ----
#pragma unroll
        for (int ri = 0; ri < 2; ++ri)
#pragma unroll
            for (int b = 0; b < 4; ++b)
                part[(size_t)(b * 64 + rq + 16 * (2 * rh + ri)) * 17 + kq] = acc[ri][b];
        __syncthreads();
        if (tid < 256) {
            float s = bias;
#pragma unroll
            for (int k2 = 0; k2 < 16; ++k2) s += part[(size_t)tid * 17 + k2];
            const float hv = tanhf(s);
            hout[tid] = (_Float16)hv;   // |hv|<=1 -> never the 0xFFFF sentinel
            const int rowg = rb * 64 + (tid & 63);
            const int bo = g * GB + (tid >> 6);
            if (l == 1) out[((size_t)bo * Tlen + t) * HD + rowg] = hv;
            if (t == Tlen - 1)
                out[(size_t)Bsz * Tlen * HD + ((size_t)l * Bsz + bo) * HD + rowg] = hv;
        }
        __syncthreads();

        // ---- publish 512B h-slice: fire-and-forget (no drain, no flag) ----
        if (tid < 32) {
            u32x4 v = *(const u32x4*)&hout[(tid >> 3) * 64 + (tid & 7) * 8];
            mall_st16(ringo + ((size_t)t * Bsz + g * GB + (tid >> 3)) * HD + rb * 64 + (tid & 7) * 8, v);
        }
    }
}

// ===========================================================================
// FALLBACK: the proven 1667us baseline, verbatim (flag protocol, RING=16).
// Selected on the host when ws_size < 64MB.
// ===========================================================================
__device__ __forceinline__ void poll2(unsigned* a, unsigned* b) {
    const int ln = threadIdx.x;  // caller guarantees < 64
    unsigned* fp = nullptr;
    if (ln < 8)       { if (a) fp = a + ln; }
    else if (ln < 16) { if (b) fp = b + (ln - 8); }
    for (;;) {
        unsigned v = fp ? mall_ld4(fp) : 1u;
        if (!__any((int)(v != 1u))) break;
        __builtin_amdgcn_s_sleep(1);
    }
}

__global__ __launch_bounds__(512, 1) void rnn_chain(
    const float* __restrict__ x, const float* __restrict__ h0in,
    const float* __restrict__ Wih, const float* __restrict__ bih,
    const float* __restrict__ Whh, const float* __restrict__ bhh,
    _Float16* __restrict__ H0r, _Float16* __restrict__ H1r,
    unsigned* f0, unsigned* f1, float* __restrict__ out)
{
    __shared__ _Float16 inb[128 * GB * 8] __attribute__((aligned(16)));
    __shared__ float    part[256 * 17];
    __shared__ _Float16 hout[256] __attribute__((aligned(16)));

    const int bid = blockIdx.x;
    const int g   = bid & 15;
    const int sl  = bid >> 4;
    const int l   = sl >> 3;
    const int rb  = sl & 7;
    const int tid = threadIdx.x;
    const int rh = tid >> 8, kq = (tid >> 4) & 15, rq = tid & 15;

    u32x4 wreg[16];
    {
        const float* WI = Wih + (size_t)l * HD * HD;
        const float* WH = Whh + (size_t)l * HD * HD;
#pragma unroll
        for (int ph = 0; ph < 2; ++ph) {
            const float* W = ph ? WH : WI;
#pragma unroll
            for (int i = 0; i < 4; ++i)
#pragma unroll
                for (int ri = 0; ri < 2; ++ri) {
                    const int row = rb * 64 + rq + 16 * (2 * rh + ri);
                    const float* p = W + (size_t)row * HD + (kq + 16 * i) * 8;
                    union { u32x4 u; _Float16 h[8]; } v;
#pragma unroll
                    for (int e = 0; e < 8; ++e) v.h[e] = (_Float16)p[e];
                    wreg[ph * 8 + i * 2 + ri] = v.u;
                }
        }
    }

    float bias = 0.f;
    if (tid < 256) {
        const int rowg = rb * 64 + (tid & 63);
        bias = bih[l * HD + rowg] + bhh[l * HD + rowg];
    }

    unsigned* fown = (l ? f1 : f0) + ((size_t)g * Tlen) * 8 + rb;
    _Float16* ringo = l ? H1r : H0r;
    const u32x4* Ip = (const u32x4*)inb;

    const int bb = tid >> 7;
    const int k4 = tid & 127;
    const int bglobS = g * GB + bb;

    float4 xreg;
    if (l == 0) xreg = *(const float4*)(x + (size_t)bglobS * Tlen * HD + k4 * 4);

    for (int t = 0; t < Tlen; ++t) {
        const int slot = t & (RING - 1);
        float acc[2][4] = {{0, 0, 0, 0}, {0, 0, 0, 0}};

        if (l == 0) {
            cvt4s(&inb[((k4 >> 1) * GB + bb) * 8 + (k4 & 1) * 4], xreg);
            __syncthreads();
            if (t + 1 < Tlen)
                xreg = *(const float4*)(x + ((size_t)bglobS * Tlen + t + 1) * HD + k4 * 4);
            gemm4(Ip, wreg, kq, 0, acc);
            if (tid < 64)
                poll2((t > 0)     ? f0 + ((size_t)g * Tlen + (t - 1)) * 8 : nullptr,
                      (t >= RING) ? f1 + ((size_t)g * Tlen + (t - RING)) * 8 : nullptr);
            __syncthreads();
            if (t == 0) {
                if (tid < 256) {
                    int b2 = tid >> 6, k8 = tid & 63;
                    const float* src = h0in + (size_t)(g * GB + b2) * HD + k8 * 8;
                    cvt4s(&inb[((64 + k8) * GB + b2) * 8],     *(const float4*)src);
                    cvt4s(&inb[((64 + k8) * GB + b2) * 8 + 4], *(const float4*)(src + 4));
                }
            } else if (tid < 256) {
                int b2 = tid >> 6, k8 = tid & 63;
                u32x4 v = mall_ld16(H0r + ((size_t)((t - 1) & (RING - 1)) * Bsz + g * GB + b2) * HD + k8 * 8);
                *(u32x4*)&inb[((64 + k8) * GB + b2) * 8] = v;
            }
            __syncthreads();
            gemm4(Ip, wreg + 8, kq, 64, acc);
        } else {
            if (tid < 64)
                poll2(f0 + ((size_t)g * Tlen + t) * 8,
                      (t > 0) ? f1 + ((size_t)g * Tlen + (t - 1)) * 8 : nullptr);
            __syncthreads();
            if (tid < 256) {
                int b2 = tid >> 6, k8 = tid & 63;
                u32x4 v = mall_ld16(H0r + ((size_t)slot * Bsz + g * GB + b2) * HD + k8 * 8);
                *(u32x4*)&inb[(k8 * GB + b2) * 8] = v;
            } else if (t == 0) {
                int t2 = tid - 256; int b2 = t2 >> 6, k8 = t2 & 63;
                const float* src = h0in + (size_t)(Bsz + g * GB + b2) * HD + k8 * 8;
                cvt4s(&inb[((64 + k8) * GB + b2) * 8],     *(const float4*)src);
                cvt4s(&inb[((64 + k8) * GB + b2) * 8 + 4], *(const float4*)(src + 4));
            } else {
                int t2 = tid - 256; int b2 = t2 >> 6, k8 = t2 & 63;
                u32x4 v = mall_ld16(H1r + ((size_t)((t - 1) & (RING - 1)) * Bsz + g * GB + b2) * HD + k8 * 8);
                *(u32x4*)&inb[((64 + k8) * GB + b2) * 8] = v;
            }
            __syncthreads();
            gemm4(Ip, wreg, kq, 0, acc);
            gemm4(Ip, wreg + 8, kq, 64, acc);
        }

#pragma unroll
        for (int ri = 0; ri < 2; ++ri)
#pragma unroll
            for (int b = 0; b < 4; ++b)
                part[(size_t)(b * 64 + rq + 16 * (2 * rh + ri)) * 17 + kq] = acc[ri][b];
        __syncthreads();
        if (tid < 256) {
            float s = bias;
#pragma unroll
            for (int k2 = 0; k2 < 16; ++k2) s += part[(size_t)tid * 17 + k2];
            const float hv = tanhf(s);
            hout[tid] = (_Float16)hv;
            const int rowg = rb * 64 + (tid & 63);
            const int bo = g * GB + (tid >> 6);
            if (l == 1) out[((size_t)bo * Tlen + t) * HD + rowg] = hv;
            if (t == Tlen - 1)
                out[(size_t)Bsz * Tlen * HD + ((size_t)l * Bsz + bo) * HD + rowg] = hv;
        }
        __syncthreads();

        if (tid < 32) {
            u32x4 v = *(const u32x4*)&hout[(tid >> 3) * 64 + (tid & 7) * 8];
            mall_st16(ringo + ((size_t)slot * Bsz + g * GB + (tid >> 3)) * HD + rb * 64 + (tid & 7) * 8, v);
        }
        if (tid < 64) {
            asm volatile("s_waitcnt vmcnt(0)" ::: "memory");
            if (tid == 0) mall_st4(fown + (size_t)t * 8, 1u);
        }
    }
}

extern "C" void kernel_launch(void* const* d_in, const int* in_sizes, int n_in,
                              void* d_out, int out_size, void* d_ws, size_t ws_size,
                              hipStream_t stream) {
    const float* x   = (const float*)d_in[0];
    const float* h0  = (const float*)d_in[1];
    const float* Wih = (const float*)d_in[2];
    const float* bih = (const float*)d_in[3];
    const float* Whh = (const float*)d_in[4];
    const float* bhh = (const float*)d_in[5];
    float* out = (float*)d_out;
    char* ws = (char*)d_ws;

    const size_t ring_bytes = (size_t)Tlen * Bsz * HD * sizeof(_Float16);  // 32MB

    if (ws_size >= 2 * ring_bytes) {
        // Fast path: full-length sentinel rings; wiped to 0xFF every launch.
        _Float16* H0r = (_Float16*)ws;
        _Float16* H1r = (_Float16*)(ws + ring_bytes);
        (void)hipMemsetAsync(ws, 0xFF, 2 * ring_bytes, stream);
        void* args[] = { (void*)&x, (void*)&h0, (void*)&Wih, (void*)&bih,
                         (void*)&Whh, (void*)&bhh, (void*)&H0r, (void*)&H1r,
                         (void*)&out };
        (void)hipLaunchCooperativeKernel((const void*)rnn_fullring, dim3(256),
                                         dim3(512), args, 0, stream);
    } else {
        // Fallback: proven baseline protocol.
        unsigned* f0  = (unsigned*)ws;
        unsigned* f1  = (unsigned*)(ws + (256u << 10));
        _Float16* H0r = (_Float16*)(ws + (512u << 10));
        _Float16* H1r = (_Float16*)(ws + (512u << 10) + (1u << 20));
        (void)hipMemsetAsync(ws, 0, 512u << 10, stream);
        void* args[] = { (void*)&x, (void*)&h0, (void*)&Wih, (void*)&bih,
                         (void*)&Whh, (void*)&bhh, (void*)&H0r, (void*)&H1r,
                         (void*)&f0, (void*)&f1, (void*)&out };
        (void)hipLaunchCooperativeKernel((const void*)rnn_chain, dim3(256),
                                         dim3(512), args, 0, stream);
    }
}